// Round 1
// baseline (1209.365 us; speedup 1.0000x reference)
//
#include <hip/hip_runtime.h>

// GCNConv: out = D^-1/2 (A + I) D^-1/2 (x W) + bias
// N = 10000, E = 640000, D_IN = D_OUT = 128, all fp32.
//
// Pipeline:
//   K1 deg_init:   deg[i] = 1.0 (self-loop)
//   K2 deg_accum:  deg[row[e]] += 1 (float atomics; exact for small counts)
//   K3 dis:        deg[i] = rsqrt(deg[i])   (in-place; deg >= 1 so no inf)
//   K4 gemm:       h = x @ W   (x tile in LDS, W streamed from global/L1/L2)
//   K5 init_out:   out[i][:] = h[i][:] * dis[i]^2 + bias   (self-loop + bias)
//   K6 scatter:    out[col[e]][:] += h[row[e]][:] * dis[r]*dis[c]  (atomics)

#define DOUT 128
#define DOUT4 32

__global__ void deg_init_kernel(float* __restrict__ deg, int n) {
    int i = blockIdx.x * blockDim.x + threadIdx.x;
    if (i < n) deg[i] = 1.0f;
}

__global__ void deg_accum_kernel(const int* __restrict__ row, float* __restrict__ deg, int e) {
    int i = blockIdx.x * blockDim.x + threadIdx.x;
    if (i < e) atomicAdd(&deg[row[i]], 1.0f);
}

__global__ void dis_kernel(float* __restrict__ deg, int n) {
    int i = blockIdx.x * blockDim.x + threadIdx.x;
    if (i < n) deg[i] = rsqrtf(deg[i]);
}

// 256 threads/block, 8 rows/block. Each thread owns (local_row = tid/32,
// float4-column c4 = tid%32). W rows read as coalesced float4 (hot in L1/L2).
__global__ void gemm_kernel(const float* __restrict__ x, const float* __restrict__ W,
                            float* __restrict__ h, int n) {
    __shared__ float xs[8 * 128];
    const int tid = threadIdx.x;
    const int rowBase = blockIdx.x * 8;

    for (int idx = tid; idx < 8 * 128; idx += 256) {
        int r = rowBase + (idx >> 7);
        xs[idx] = (r < n) ? x[r * 128 + (idx & 127)] : 0.0f;
    }
    __syncthreads();

    const int lr = tid >> 5;   // 0..7
    const int c4 = tid & 31;   // 0..31
    const int row = rowBase + lr;

    const float4* __restrict__ W4 = (const float4*)W;
    float4 acc = make_float4(0.f, 0.f, 0.f, 0.f);
#pragma unroll 8
    for (int k = 0; k < 128; ++k) {
        float xv = xs[lr * 128 + k];
        float4 wv = W4[k * DOUT4 + c4];
        acc.x = fmaf(xv, wv.x, acc.x);
        acc.y = fmaf(xv, wv.y, acc.y);
        acc.z = fmaf(xv, wv.z, acc.z);
        acc.w = fmaf(xv, wv.w, acc.w);
    }
    if (row < n) ((float4*)h)[row * DOUT4 + c4] = acc;
}

__global__ void init_out_kernel(const float* __restrict__ h, const float* __restrict__ dis,
                                const float* __restrict__ bias, float* __restrict__ out, int n) {
    int idx = blockIdx.x * blockDim.x + threadIdx.x;  // over n*128
    if (idx < n * 128) {
        int i = idx >> 7;
        int j = idx & 127;
        float di = dis[i];
        out[idx] = h[idx] * di * di + bias[j];
    }
}

// 32 threads per edge; each thread gathers one float4 of h[row] and issues
// 4 scalar fp32 atomics into out[col].
__global__ void scatter_kernel(const int* __restrict__ row, const int* __restrict__ col,
                               const float* __restrict__ h, const float* __restrict__ dis,
                               float* __restrict__ out, int e) {
    int gid = blockIdx.x * blockDim.x + threadIdx.x;
    int ed = gid >> 5;
    int c4 = gid & 31;
    if (ed >= e) return;
    int r = row[ed];
    int c = col[ed];
    float w = dis[r] * dis[c];
    float4 hv = ((const float4*)h)[r * DOUT4 + c4];
    float* o = out + c * 128 + c4 * 4;
    atomicAdd(o + 0, hv.x * w);
    atomicAdd(o + 1, hv.y * w);
    atomicAdd(o + 2, hv.z * w);
    atomicAdd(o + 3, hv.w * w);
}

extern "C" void kernel_launch(void* const* d_in, const int* in_sizes, int n_in,
                              void* d_out, int out_size, void* d_ws, size_t ws_size,
                              hipStream_t stream) {
    const float* x    = (const float*)d_in[0];
    const int*   ei   = (const int*)d_in[1];
    const float* W    = (const float*)d_in[2];
    const float* bias = (const float*)d_in[3];
    float* out = (float*)d_out;

    const int N = in_sizes[0] / 128;   // 10000
    const int E = in_sizes[1] / 2;     // 640000
    const int* row = ei;
    const int* col = ei + E;

    // Workspace layout: [deg/dis: N floats][pad to 64KB][h: N*128 floats]
    float* deg = (float*)d_ws;
    float* h   = (float*)((char*)d_ws + 64 * 1024);

    deg_init_kernel<<<(N + 255) / 256, 256, 0, stream>>>(deg, N);
    deg_accum_kernel<<<(E + 255) / 256, 256, 0, stream>>>(row, deg, E);
    dis_kernel<<<(N + 255) / 256, 256, 0, stream>>>(deg, N);
    gemm_kernel<<<(N + 7) / 8, 256, 0, stream>>>(x, W, h, N);
    init_out_kernel<<<(N * 128 + 255) / 256, 256, 0, stream>>>(h, deg, bias, out, N);

    long long scatter_threads = (long long)E * 32;
    scatter_kernel<<<(int)((scatter_threads + 255) / 256), 256, 0, stream>>>(
        row, col, h, deg, out, E);
}

// Round 2
// 260.336 us; speedup vs baseline: 4.6454x; 4.6454x over previous
//
#include <hip/hip_runtime.h>

// GCNConv: out = D^-1/2 (A + I) D^-1/2 (x W) + bias
// N = 10000, E = 640000, D_IN = D_OUT = 128, fp32.
//
// Round 2: replace 82M-atomic scatter with destination-CSR + wave-per-node
// gather (zero atomics on the output).
//
// Pipeline:
//   K1 setup:  deg[i]=1 (self-loop), indeg[i]=0, cursor[i]=0
//   K2 hist:   deg[row[e]] += 1 (norm degree), indeg[col[e]] += 1 (CSR count)
//   K3 dis:    deg[i] = rsqrt(deg[i])
//   K4 scan:   off = exclusive_scan(indeg)          (single block)
//   K5 fill:   bucket-fill csr_src / csr_w by destination
//   K6 gemm:   h = x @ W
//   K7 gather: wave per dest node: acc = h[c]*dis[c]^2 + bias
//                                  + sum_e h[src_e] * w_e ; one clean write.

#define DOUT 128

__global__ void setup_kernel(float* __restrict__ deg, int* __restrict__ indeg,
                             int* __restrict__ cursor, int n) {
    int i = blockIdx.x * blockDim.x + threadIdx.x;
    if (i < n) { deg[i] = 1.0f; indeg[i] = 0; cursor[i] = 0; }
}

__global__ void hist_kernel(const int* __restrict__ row, const int* __restrict__ col,
                            float* __restrict__ deg, int* __restrict__ indeg, int e) {
    int i = blockIdx.x * blockDim.x + threadIdx.x;
    if (i < e) {
        atomicAdd(&deg[row[i]], 1.0f);   // exact: counts << 2^24
        atomicAdd(&indeg[col[i]], 1);
    }
}

__global__ void dis_kernel(float* __restrict__ deg, int n) {
    int i = blockIdx.x * blockDim.x + threadIdx.x;
    if (i < n) deg[i] = rsqrtf(deg[i]);
}

// Single-block exclusive scan over n (n <= 1024*CHUNK). 1024 threads.
__global__ void scan_kernel(const int* __restrict__ cnt, int* __restrict__ off, int n) {
    __shared__ int partial[1024];
    const int tid = threadIdx.x;
    const int chunk = (n + 1023) >> 10;
    const int begin = min(tid * chunk, n);
    const int end = min(begin + chunk, n);
    int sum = 0;
    for (int i = begin; i < end; ++i) sum += cnt[i];
    partial[tid] = sum;
    __syncthreads();
    for (int ofs = 1; ofs < 1024; ofs <<= 1) {
        int v = (tid >= ofs) ? partial[tid - ofs] : 0;
        __syncthreads();
        partial[tid] += v;
        __syncthreads();
    }
    int run = (tid > 0) ? partial[tid - 1] : 0;
    for (int i = begin; i < end; ++i) {
        off[i] = run;
        run += cnt[i];
    }
    if (tid == 1023) off[n] = partial[1023];
}

__global__ void fill_kernel(const int* __restrict__ row, const int* __restrict__ col,
                            const float* __restrict__ dis, const int* __restrict__ off,
                            int* __restrict__ cursor, int* __restrict__ csr_src,
                            float* __restrict__ csr_w, int e) {
    int i = blockIdx.x * blockDim.x + threadIdx.x;
    if (i >= e) return;
    int r = row[i], c = col[i];
    int pos = atomicAdd(&cursor[c], 1);
    int idx = off[c] + pos;
    csr_src[idx] = r;
    csr_w[idx] = dis[r] * dis[c];
}

// 256 threads/block, 8 rows/block; thread owns (row tid/32, float4-col tid%32).
__global__ void gemm_kernel(const float* __restrict__ x, const float* __restrict__ W,
                            float* __restrict__ h, int n) {
    __shared__ float xs[8 * 128];
    const int tid = threadIdx.x;
    const int rowBase = blockIdx.x * 8;

    for (int idx = tid; idx < 8 * 128; idx += 256) {
        int r = rowBase + (idx >> 7);
        xs[idx] = (r < n) ? x[r * 128 + (idx & 127)] : 0.0f;
    }
    __syncthreads();

    const int lr = tid >> 5;
    const int c4 = tid & 31;
    const int row = rowBase + lr;

    const float4* __restrict__ W4 = (const float4*)W;
    float4 acc = make_float4(0.f, 0.f, 0.f, 0.f);
#pragma unroll 8
    for (int k = 0; k < 128; ++k) {
        float xv = xs[lr * 128 + k];
        float4 wv = W4[k * 32 + c4];
        acc.x = fmaf(xv, wv.x, acc.x);
        acc.y = fmaf(xv, wv.y, acc.y);
        acc.z = fmaf(xv, wv.z, acc.z);
        acc.w = fmaf(xv, wv.w, acc.w);
    }
    if (row < n) ((float4*)h)[row * 32 + c4] = acc;
}

// One wave (64 lanes) per destination node; lane owns float2 of columns.
__global__ void gather_kernel(const int* __restrict__ off, const int* __restrict__ csr_src,
                              const float* __restrict__ csr_w, const float* __restrict__ h,
                              const float* __restrict__ dis, const float* __restrict__ bias,
                              float* __restrict__ out, int n) {
    const int wave = (blockIdx.x * blockDim.x + threadIdx.x) >> 6;
    const int lane = threadIdx.x & 63;
    if (wave >= n) return;
    const int c = wave;
    const float2* __restrict__ h2 = (const float2*)h;

    float dc = dis[c];
    float2 hv = h2[c * 64 + lane];
    float2 bv = ((const float2*)bias)[lane];
    float2 acc;
    acc.x = fmaf(hv.x, dc * dc, bv.x);
    acc.y = fmaf(hv.y, dc * dc, bv.y);

    const int start = off[c];
    const int end = off[c + 1];
    for (int base = start; base < end; base += 64) {
        int idx = base + lane;
        int src = 0;
        float w = 0.0f;
        if (idx < end) { src = csr_src[idx]; w = csr_w[idx]; }
        const int cnt = min(64, end - base);
        for (int j = 0; j < cnt; ++j) {
            int r = __shfl(src, j);
            float wj = __shfl(w, j);
            float2 hr = h2[r * 64 + lane];
            acc.x = fmaf(hr.x, wj, acc.x);
            acc.y = fmaf(hr.y, wj, acc.y);
        }
    }
    ((float2*)out)[c * 64 + lane] = acc;
}

extern "C" void kernel_launch(void* const* d_in, const int* in_sizes, int n_in,
                              void* d_out, int out_size, void* d_ws, size_t ws_size,
                              hipStream_t stream) {
    const float* x    = (const float*)d_in[0];
    const int*   ei   = (const int*)d_in[1];
    const float* W    = (const float*)d_in[2];
    const float* bias = (const float*)d_in[3];
    float* out = (float*)d_out;

    const int N = in_sizes[0] / 128;   // 10000
    const int E = in_sizes[1] / 2;     // 640000
    const int* row = ei;
    const int* col = ei + E;

    // Workspace layout (256B-aligned chunks):
    auto align256 = [](size_t v) { return (v + 255) & ~(size_t)255; };
    char* p = (char*)d_ws;
    float* deg     = (float*)p;                      p += align256((size_t)N * 4);
    int*   indeg   = (int*)p;                        p += align256((size_t)N * 4);
    int*   cursor  = (int*)p;                        p += align256((size_t)N * 4);
    int*   off     = (int*)p;                        p += align256((size_t)(N + 1) * 4);
    int*   csr_src = (int*)p;                        p += align256((size_t)E * 4);
    float* csr_w   = (float*)p;                      p += align256((size_t)E * 4);
    float* h       = (float*)p;                      p += align256((size_t)N * DOUT * 4);

    setup_kernel<<<(N + 255) / 256, 256, 0, stream>>>(deg, indeg, cursor, N);
    hist_kernel<<<(E + 255) / 256, 256, 0, stream>>>(row, col, deg, indeg, E);
    dis_kernel<<<(N + 255) / 256, 256, 0, stream>>>(deg, N);
    scan_kernel<<<1, 1024, 0, stream>>>(indeg, off, N);
    fill_kernel<<<(E + 255) / 256, 256, 0, stream>>>(row, col, deg, off, cursor,
                                                     csr_src, csr_w, E);
    gemm_kernel<<<(N + 7) / 8, 256, 0, stream>>>(x, W, h, N);

    long long gthreads = (long long)N * 64;
    gather_kernel<<<(int)((gthreads + 255) / 256), 256, 0, stream>>>(
        off, csr_src, csr_w, h, deg, bias, out, N);
}

// Round 3
// 209.755 us; speedup vs baseline: 5.7656x; 1.2411x over previous
//
#include <hip/hip_runtime.h>

// GCNConv: out = D^-1/2 (A + I) D^-1/2 (x W) + bias
// N = 10000, E = 640000, D_IN = D_OUT = 128, fp32.
//
// Round 3: atomic-contention fix.
//  - K-way replicated histograms (k-major: rep[k][N]) -> 16x fewer atomics
//    per L2 cache line.
//  - hist also records rank[e] = position within (k, dest) bucket, so the
//    CSR fill pass needs NO atomics at all:
//      slot = off[c] + suboff[k][c] + rank[e]
//  - gather: 4x-unrolled broadcast loop for load-level parallelism.

#define DOUT 128
#define KREP 16

__global__ void zero_kernel(int* __restrict__ p, int n) {
    int i = blockIdx.x * blockDim.x + threadIdx.x;
    if (i < n) p[i] = 0;
}

// outdeg_rep[k][r] += 1 ; rank[e] = indeg_rep[k][c]++ (k = e & 15)
__global__ void hist_kernel(const int* __restrict__ row, const int* __restrict__ col,
                            int* __restrict__ outdeg_rep, int* __restrict__ indeg_rep,
                            int* __restrict__ rank, int n, int e) {
    int i = blockIdx.x * blockDim.x + threadIdx.x;
    if (i >= e) return;
    int r = row[i], c = col[i], k = i & (KREP - 1);
    atomicAdd(&outdeg_rep[k * n + r], 1);
    rank[i] = atomicAdd(&indeg_rep[k * n + c], 1);
}

// Per node: dis = rsqrt(1 + sum_k outdeg_rep); turn indeg_rep slices into
// per-node exclusive prefix (suboff) in place; indeg[c] = total.
__global__ void scan_prep_kernel(int* __restrict__ outdeg_rep, int* __restrict__ indeg_rep,
                                 float* __restrict__ dis, int* __restrict__ indeg, int n) {
    int c = blockIdx.x * blockDim.x + threadIdx.x;
    if (c >= n) return;
    int s = 0;
#pragma unroll
    for (int k = 0; k < KREP; ++k) s += outdeg_rep[k * n + c];
    dis[c] = rsqrtf(1.0f + (float)s);
    int run = 0;
#pragma unroll
    for (int k = 0; k < KREP; ++k) {
        int v = indeg_rep[k * n + c];
        indeg_rep[k * n + c] = run;   // becomes suboff[k][c]
        run += v;
    }
    indeg[c] = run;
}

// Single-block exclusive scan over n. 1024 threads.
__global__ void scan_kernel(const int* __restrict__ cnt, int* __restrict__ off, int n) {
    __shared__ int partial[1024];
    const int tid = threadIdx.x;
    const int chunk = (n + 1023) >> 10;
    const int begin = min(tid * chunk, n);
    const int end = min(begin + chunk, n);
    int sum = 0;
    for (int i = begin; i < end; ++i) sum += cnt[i];
    partial[tid] = sum;
    __syncthreads();
    for (int ofs = 1; ofs < 1024; ofs <<= 1) {
        int v = (tid >= ofs) ? partial[tid - ofs] : 0;
        __syncthreads();
        partial[tid] += v;
        __syncthreads();
    }
    int run = (tid > 0) ? partial[tid - 1] : 0;
    for (int i = begin; i < end; ++i) {
        off[i] = run;
        run += cnt[i];
    }
    if (tid == 1023) off[n] = partial[1023];
}

// Atomic-free CSR fill: slot = off[c] + suboff[k][c] + rank[e]
__global__ void fill_kernel(const int* __restrict__ row, const int* __restrict__ col,
                            const float* __restrict__ dis, const int* __restrict__ off,
                            const int* __restrict__ suboff, const int* __restrict__ rank,
                            int* __restrict__ csr_src, float* __restrict__ csr_w,
                            int n, int e) {
    int i = blockIdx.x * blockDim.x + threadIdx.x;
    if (i >= e) return;
    int r = row[i], c = col[i], k = i & (KREP - 1);
    int idx = off[c] + suboff[k * n + c] + rank[i];
    csr_src[idx] = r;
    csr_w[idx] = dis[r] * dis[c];
}

// 256 threads/block, 8 rows/block; thread owns (row tid/32, float4-col tid%32).
__global__ void gemm_kernel(const float* __restrict__ x, const float* __restrict__ W,
                            float* __restrict__ h, int n) {
    __shared__ float xs[8 * 128];
    const int tid = threadIdx.x;
    const int rowBase = blockIdx.x * 8;

    for (int idx = tid; idx < 8 * 128; idx += 256) {
        int r = rowBase + (idx >> 7);
        xs[idx] = (r < n) ? x[r * 128 + (idx & 127)] : 0.0f;
    }
    __syncthreads();

    const int lr = tid >> 5;
    const int c4 = tid & 31;
    const int row = rowBase + lr;

    const float4* __restrict__ W4 = (const float4*)W;
    float4 acc = make_float4(0.f, 0.f, 0.f, 0.f);
#pragma unroll 8
    for (int k = 0; k < 128; ++k) {
        float xv = xs[lr * 128 + k];
        float4 wv = W4[k * 32 + c4];
        acc.x = fmaf(xv, wv.x, acc.x);
        acc.y = fmaf(xv, wv.y, acc.y);
        acc.z = fmaf(xv, wv.z, acc.z);
        acc.w = fmaf(xv, wv.w, acc.w);
    }
    if (row < n) ((float4*)h)[row * 32 + c4] = acc;
}

// One wave per destination node; lane owns a float2 of columns.
// Invalid lanes carry w=0, src=0 so the unrolled loop needs no tail logic.
__global__ void gather_kernel(const int* __restrict__ off, const int* __restrict__ csr_src,
                              const float* __restrict__ csr_w, const float* __restrict__ h,
                              const float* __restrict__ dis, const float* __restrict__ bias,
                              float* __restrict__ out, int n) {
    const int wave = (blockIdx.x * blockDim.x + threadIdx.x) >> 6;
    const int lane = threadIdx.x & 63;
    if (wave >= n) return;
    const int c = wave;
    const float2* __restrict__ h2 = (const float2*)h;

    float dc = dis[c];
    float2 hv = h2[c * 64 + lane];
    float2 bv = ((const float2*)bias)[lane];
    float2 acc;
    acc.x = fmaf(hv.x, dc * dc, bv.x);
    acc.y = fmaf(hv.y, dc * dc, bv.y);

    const int start = off[c];
    const int end = off[c + 1];
    for (int base = start; base < end; base += 64) {
        int idx = base + lane;
        int src = 0;
        float w = 0.0f;
        if (idx < end) { src = csr_src[idx]; w = csr_w[idx]; }
        int cnt = min(64, end - base);
        int cnt4 = (cnt + 3) & ~3;   // lanes >= cnt have w=0: harmless
        for (int j = 0; j < cnt4; j += 4) {
            int r0 = __shfl(src, j + 0); float w0 = __shfl(w, j + 0);
            int r1 = __shfl(src, j + 1); float w1 = __shfl(w, j + 1);
            int r2 = __shfl(src, j + 2); float w2 = __shfl(w, j + 2);
            int r3 = __shfl(src, j + 3); float w3 = __shfl(w, j + 3);
            float2 h0 = h2[r0 * 64 + lane];
            float2 h1 = h2[r1 * 64 + lane];
            float2 h2v = h2[r2 * 64 + lane];
            float2 h3 = h2[r3 * 64 + lane];
            acc.x = fmaf(h0.x, w0, acc.x);  acc.y = fmaf(h0.y, w0, acc.y);
            acc.x = fmaf(h1.x, w1, acc.x);  acc.y = fmaf(h1.y, w1, acc.y);
            acc.x = fmaf(h2v.x, w2, acc.x); acc.y = fmaf(h2v.y, w2, acc.y);
            acc.x = fmaf(h3.x, w3, acc.x);  acc.y = fmaf(h3.y, w3, acc.y);
        }
    }
    ((float2*)out)[c * 64 + lane] = acc;
}

extern "C" void kernel_launch(void* const* d_in, const int* in_sizes, int n_in,
                              void* d_out, int out_size, void* d_ws, size_t ws_size,
                              hipStream_t stream) {
    const float* x    = (const float*)d_in[0];
    const int*   ei   = (const int*)d_in[1];
    const float* W    = (const float*)d_in[2];
    const float* bias = (const float*)d_in[3];
    float* out = (float*)d_out;

    const int N = in_sizes[0] / 128;   // 10000
    const int E = in_sizes[1] / 2;     // 640000
    const int* row = ei;
    const int* col = ei + E;

    auto align256 = [](size_t v) { return (v + 255) & ~(size_t)255; };
    char* p = (char*)d_ws;
    int*   outdeg_rep = (int*)p;   p += align256((size_t)KREP * N * 4);  // 640 KB
    int*   indeg_rep  = (int*)p;   p += align256((size_t)KREP * N * 4);  // 640 KB (-> suboff)
    float* dis        = (float*)p; p += align256((size_t)N * 4);
    int*   indeg      = (int*)p;   p += align256((size_t)N * 4);
    int*   off        = (int*)p;   p += align256((size_t)(N + 1) * 4);
    int*   rank       = (int*)p;   p += align256((size_t)E * 4);         // 2.56 MB
    int*   csr_src    = (int*)p;   p += align256((size_t)E * 4);         // 2.56 MB
    float* csr_w      = (float*)p; p += align256((size_t)E * 4);         // 2.56 MB
    float* h          = (float*)p; p += align256((size_t)N * DOUT * 4);  // 5.12 MB

    const int zn = 2 * KREP * N;  // outdeg_rep + indeg_rep (contiguous)
    zero_kernel<<<(zn + 255) / 256, 256, 0, stream>>>(outdeg_rep, zn);
    hist_kernel<<<(E + 255) / 256, 256, 0, stream>>>(row, col, outdeg_rep, indeg_rep,
                                                     rank, N, E);
    scan_prep_kernel<<<(N + 255) / 256, 256, 0, stream>>>(outdeg_rep, indeg_rep,
                                                          dis, indeg, N);
    scan_kernel<<<1, 1024, 0, stream>>>(indeg, off, N);
    fill_kernel<<<(E + 255) / 256, 256, 0, stream>>>(row, col, dis, off, indeg_rep,
                                                     rank, csr_src, csr_w, N, E);
    gemm_kernel<<<(N + 7) / 8, 256, 0, stream>>>(x, W, h, N);

    long long gthreads = (long long)N * 64;
    gather_kernel<<<(int)((gthreads + 255) / 256), 256, 0, stream>>>(
        off, csr_src, csr_w, h, dis, bias, out, N);
}

// Round 4
// 180.906 us; speedup vs baseline: 6.6851x; 1.1595x over previous
//
#include <hip/hip_runtime.h>

// GCNConv: out = D^-1/2 (A + I) D^-1/2 (x W) + bias
// N = 10000, E = 640000, D_IN = D_OUT = 128, fp32.
//
// Round 4: ZERO global atomics.
//  - hist: 128 blocks, per-block LDS histograms (out-deg 40KB + in-deg 40KB),
//    rank[e] = LDS-atomic return. Partials written coalesced (no atomics).
//  - reduce: per-node sum of out-partials -> dis; per-node exclusive prefix
//    over in-partials (in place -> suboff); indeg totals.
//  - scan: shfl-based single-block exclusive scan -> off.
//  - fill: slot = off[c] + suboff[b][c] + rank[e]  (atomic-free, src only;
//    weights not stored: dis folded into g and applied at gather epilogue).
//  - gemm: g = (x @ W) * dis[row]   (dis fused into epilogue).
//  - gather: wave/node, float4 lanes, half-wave processes 2 edges per step:
//    out[c] = dis[c] * (sum_e g[src_e] + g[c]) + bias.

#define NNODES 10000
#define NB 128          // histogram blocks (EPB = 5000)
#define DOUT 128

__global__ __launch_bounds__(256, 2) void hist_kernel(
    const int* __restrict__ row, const int* __restrict__ col,
    int* __restrict__ partial_out, int* __restrict__ partial_in,
    int* __restrict__ rank, int N, int E, int EPB) {
    __shared__ int ho[NNODES];
    __shared__ int hi[NNODES];
    const int tid = threadIdx.x;
    const int b = blockIdx.x;
    for (int j = tid; j < N; j += 256) { ho[j] = 0; hi[j] = 0; }
    __syncthreads();
    const int begin = b * EPB;
    const int end = min(E, begin + EPB);
    for (int e = begin + tid; e < end; e += 256) {
        int r = row[e], c = col[e];
        atomicAdd(&ho[r], 1);                 // LDS atomic
        rank[e] = atomicAdd(&hi[c], 1);       // LDS atomic w/ return
    }
    __syncthreads();
    for (int j = tid; j < N; j += 256) {
        partial_out[b * N + j] = ho[j];
        partial_in[b * N + j] = hi[j];
    }
}

__global__ void reduce_kernel(const int* __restrict__ partial_out,
                              int* __restrict__ partial_in,
                              float* __restrict__ dis, int* __restrict__ indeg, int N) {
    int n = blockIdx.x * blockDim.x + threadIdx.x;
    if (n >= N) return;
    int s = 0;
#pragma unroll 16
    for (int b = 0; b < NB; ++b) s += partial_out[b * N + n];
    dis[n] = rsqrtf(1.0f + (float)s);
    int run = 0;
#pragma unroll 16
    for (int b = 0; b < NB; ++b) {
        int v = partial_in[b * N + n];
        partial_in[b * N + n] = run;          // becomes suboff[b][n]
        run += v;
    }
    indeg[n] = run;
}

// Single-block exclusive scan, 1024 threads, shfl-based.
__global__ void scan_kernel(const int* __restrict__ cnt, int* __restrict__ off, int n) {
    __shared__ int wsum[16];
    const int tid = threadIdx.x;
    const int lane = tid & 63, wid = tid >> 6;
    const int chunk = (n + 1023) >> 10;
    const int begin = min(tid * chunk, n), end = min(begin + chunk, n);
    int s = 0;
    for (int i = begin; i < end; ++i) s += cnt[i];
    const int own = s;
    for (int d = 1; d < 64; d <<= 1) {
        int v = __shfl_up(s, d);
        if (lane >= d) s += v;
    }
    if (lane == 63) wsum[wid] = s;
    __syncthreads();
    if (wid == 0) {
        int ws = (lane < 16) ? wsum[lane] : 0;
        for (int d = 1; d < 16; d <<= 1) {
            int v = __shfl_up(ws, d);
            if (lane >= d) ws += v;
        }
        if (lane < 16) wsum[lane] = ws;
    }
    __syncthreads();
    int run = (wid > 0 ? wsum[wid - 1] : 0) + (s - own);  // exclusive base
    for (int i = begin; i < end; ++i) { off[i] = run; run += cnt[i]; }
    if (tid == 1023) off[n] = run;
}

__global__ void fill_kernel(const int* __restrict__ row, const int* __restrict__ col,
                            const int* __restrict__ off, const int* __restrict__ suboff,
                            const int* __restrict__ rank, int* __restrict__ csr_src,
                            int N, int E, int EPB) {
    const int b = blockIdx.x;
    const int begin = b * EPB, end = min(E, begin + EPB);
    for (int e = begin + threadIdx.x; e < end; e += 256) {
        int r = row[e], c = col[e];
        csr_src[off[c] + suboff[b * N + c] + rank[e]] = r;
    }
}

// 256 threads/block, 8 rows/block; g[row] = (x@W)[row] * dis[row].
__global__ void gemm_kernel(const float* __restrict__ x, const float* __restrict__ W,
                            const float* __restrict__ dis, float* __restrict__ g, int n) {
    __shared__ float xs[8 * 128];
    const int tid = threadIdx.x;
    const int rowBase = blockIdx.x * 8;

    for (int idx = tid; idx < 8 * 128; idx += 256) {
        int r = rowBase + (idx >> 7);
        xs[idx] = (r < n) ? x[r * 128 + (idx & 127)] : 0.0f;
    }
    __syncthreads();

    const int lr = tid >> 5;
    const int c4 = tid & 31;
    const int row = rowBase + lr;

    const float4* __restrict__ W4 = (const float4*)W;
    float4 acc = make_float4(0.f, 0.f, 0.f, 0.f);
#pragma unroll 8
    for (int k = 0; k < 128; ++k) {
        float xv = xs[lr * 128 + k];
        float4 wv = W4[k * 32 + c4];
        acc.x = fmaf(xv, wv.x, acc.x);
        acc.y = fmaf(xv, wv.y, acc.y);
        acc.z = fmaf(xv, wv.z, acc.z);
        acc.w = fmaf(xv, wv.w, acc.w);
    }
    if (row < n) {
        float d = dis[row];
        acc.x *= d; acc.y *= d; acc.z *= d; acc.w *= d;
        ((float4*)g)[row * 32 + c4] = acc;
    }
}

// One wave per destination node. Lane layout: half = lane>>5 picks one of 2
// edges per step; l32 = lane&31 picks the float4 column chunk (32*16B = row).
__global__ void gather_kernel(const int* __restrict__ off, const int* __restrict__ csr_src,
                              const float* __restrict__ g, const float* __restrict__ dis,
                              const float* __restrict__ bias, float* __restrict__ out, int n) {
    const int wave = (blockIdx.x * blockDim.x + threadIdx.x) >> 6;
    const int lane = threadIdx.x & 63;
    if (wave >= n) return;
    const int c = wave;
    const int half = lane >> 5;
    const int l32 = lane & 31;
    const float4* __restrict__ g4 = (const float4*)g;

    float4 acc = make_float4(0.f, 0.f, 0.f, 0.f);
    if (half == 0) {  // self-loop term: + g[c]
        float4 gv = g4[c * 32 + l32];
        acc.x += gv.x; acc.y += gv.y; acc.z += gv.z; acc.w += gv.w;
    }

    const int start = off[c], end = off[c + 1];
    for (int base = start; base < end; base += 64) {
        int idx = base + lane;
        int src = (idx < end) ? csr_src[idx] : 0;
        int cnt = min(64, end - base);
#pragma unroll
        for (int t = 0; t < 64; t += 2) {
            int j = t + half;                 // half 0: even edges, half 1: odd
            int r = __shfl(src, j);
            if (j < cnt) {
                float4 gv = g4[r * 32 + l32];
                acc.x += gv.x; acc.y += gv.y; acc.z += gv.z; acc.w += gv.w;
            }
        }
    }
    // combine halves into lanes 0..31
    float ox = acc.x + __shfl(acc.x, l32 + 32);
    float oy = acc.y + __shfl(acc.y, l32 + 32);
    float oz = acc.z + __shfl(acc.z, l32 + 32);
    float ow = acc.w + __shfl(acc.w, l32 + 32);
    if (lane < 32) {
        float dc = dis[c];
        float4 bv = ((const float4*)bias)[l32];
        float4 o;
        o.x = fmaf(ox, dc, bv.x);
        o.y = fmaf(oy, dc, bv.y);
        o.z = fmaf(oz, dc, bv.z);
        o.w = fmaf(ow, dc, bv.w);
        ((float4*)out)[c * 32 + l32] = o;
    }
}

extern "C" void kernel_launch(void* const* d_in, const int* in_sizes, int n_in,
                              void* d_out, int out_size, void* d_ws, size_t ws_size,
                              hipStream_t stream) {
    const float* x    = (const float*)d_in[0];
    const int*   ei   = (const int*)d_in[1];
    const float* W    = (const float*)d_in[2];
    const float* bias = (const float*)d_in[3];
    float* out = (float*)d_out;

    const int N = in_sizes[0] / 128;   // 10000
    const int E = in_sizes[1] / 2;     // 640000
    const int* row = ei;
    const int* col = ei + E;
    const int EPB = (E + NB - 1) / NB; // 5000

    // Workspace layout (with aliasing for footprint ~13 MB):
    //  A: partial_out [NB*N] (5.12 MB)  -> dead after reduce -> csr_src aliases
    //  B: partial_in  [NB*N] (5.12 MB)  -> suboff, dead after fill -> g aliases
    //  C: rank [E] (2.56 MB)            -> dead after fill
    //  D: dis/indeg/off (small)
    auto align256 = [](size_t v) { return (v + 255) & ~(size_t)255; };
    char* p = (char*)d_ws;
    int*   partial_out = (int*)p;   p += align256((size_t)NB * N * 4);
    int*   partial_in  = (int*)p;   p += align256((size_t)NB * N * 4);
    int*   rank        = (int*)p;   p += align256((size_t)E * 4);
    float* dis         = (float*)p; p += align256((size_t)N * 4);
    int*   indeg       = (int*)p;   p += align256((size_t)N * 4);
    int*   off         = (int*)p;   p += align256((size_t)(N + 1) * 4);
    int*   csr_src     = partial_out;          // alias (A dead after reduce)
    float* g           = (float*)partial_in;   // alias (B dead after fill)

    hist_kernel<<<NB, 256, 0, stream>>>(row, col, partial_out, partial_in, rank, N, E, EPB);
    reduce_kernel<<<(N + 255) / 256, 256, 0, stream>>>(partial_out, partial_in, dis, indeg, N);
    scan_kernel<<<1, 1024, 0, stream>>>(indeg, off, N);
    fill_kernel<<<NB, 256, 0, stream>>>(row, col, off, partial_in, rank, csr_src, N, E, EPB);
    gemm_kernel<<<(N + 7) / 8, 256, 0, stream>>>(x, W, dis, g, N);

    long long gthreads = (long long)N * 64;
    gather_kernel<<<(int)((gthreads + 255) / 256), 256, 0, stream>>>(
        off, csr_src, g, dis, bias, out, N);
}